// Round 1
// baseline (351.222 us; speedup 1.0000x reference)
//
#include <hip/hip_runtime.h>
#include <math.h>

#define BB 8
#define NQ 2048
#define NK 2048
#define DD 64
#define VV 128
#define EPSF 1e-7f
#define KSPL 2   // k-range split for k1 partial row sums

typedef _Float16 half_t;
typedef half_t half8 __attribute__((ext_vector_type(8)));
typedef float  floatx4 __attribute__((ext_vector_type(4)));

// exp(-arccosh(1+tt)^2); tt from fp32 norms + fp16-MFMA cross term.
// arccosh(1+tt) = ln(1+u), u = tt + sqrt(tt*(tt+2))
// NOTE: px/py computed inline (same expression as before -> bit-identical E).
__device__ __forceinline__ float score_exp(float x2, float y2, float xy)
{
    float px = 1.f - x2, py = 1.f - y2;
    float sq = fmaxf(x2 + y2 - 2.f * xy, 0.f);
    float dn = fmaxf(px * py, EPSF);
    float tt = fmaxf(2.f * sq * __builtin_amdgcn_rcpf(dn), EPSF);
    float u  = tt + __builtin_amdgcn_sqrtf(fmaf(tt, tt, tt + tt));
    float d  = __logf(1.f + u);
    return __expf(-d * d);
}

__device__ __forceinline__ half8 cvt8(float4 a, float4 b)
{
    half8 h;
    h[0] = (half_t)a.x; h[1] = (half_t)a.y; h[2] = (half_t)a.z; h[3] = (half_t)a.w;
    h[4] = (half_t)b.x; h[5] = (half_t)b.y; h[6] = (half_t)b.z; h[7] = (half_t)b.w;
    return h;
}

__device__ __forceinline__ void store_nt4(float* p, float4 v)
{
    floatx4 t; t[0] = v.x; t[1] = v.y; t[2] = v.z; t[3] = v.w;
    __builtin_nontemporal_store(t, (floatx4*)p);
}

// ---------------------------------------------------------------------------
// K1: row sums of E over this block's NK/KSPL k-range. NO E store (E is
// recomputed in K3). Writes KSPL partial-sum arrays of B*NQ floats to ws.
// Grid (NQ/32, BB, KSPL), 256 thr = 4 waves = (q-half, k-half).
// ---------------------------------------------------------------------------
__global__ __launch_bounds__(256)
void k1_rowsum(const float* __restrict__ Q, const float* __restrict__ Kp,
               float* __restrict__ RS)
{
    __shared__ half8 sB[2][8 * 64];          // [k-half][frag*64+lane]
    __shared__ float y2k[NK / KSPL];
    __shared__ float x2q[32];
    __shared__ float part[2][32];

    const int t = threadIdx.x, w = t >> 6, lane = t & 63;
    const int n = lane & 15, quad = lane >> 4;
    const int qh = w & 1, kh = w >> 1;
    const int b = blockIdx.y, qb = blockIdx.x * 32;
    const int kz = blockIdx.z * (NK / KSPL);

    const float* Kb = Kp + (size_t)b * NK * DD;
    const float* Qb = Q  + (size_t)b * NQ * DD;

    // fp32 norms: this block's 1024 K rows (4/thread) + 32 Q rows
#pragma unroll
    for (int j = 0; j < NK / KSPL / 256; ++j) {
        int row = t + j * 256;
        const float4* kr = (const float4*)(Kb + (size_t)(kz + row) * DD);
        float s = 0.f;
#pragma unroll
        for (int i = 0; i < 16; ++i) {
            float4 v = kr[i];
            s = fmaf(v.x,v.x,s); s = fmaf(v.y,v.y,s);
            s = fmaf(v.z,v.z,s); s = fmaf(v.w,v.w,s);
        }
        y2k[row] = s;
    }
    if (t < 32) {
        const float4* qr = (const float4*)(Qb + (size_t)(qb + t) * DD);
        float s = 0.f;
#pragma unroll
        for (int i = 0; i < 16; ++i) {
            float4 v = qr[i];
            s = fmaf(v.x,v.x,s); s = fmaf(v.y,v.y,s);
            s = fmaf(v.z,v.z,s); s = fmaf(v.w,v.w,s);
        }
        x2q[t] = s;
    }
    __syncthreads();

    // A-frags: lane holds Q[qb + qh*16 + n][ds*32 + quad*8 + j]
    half8 af[2];
#pragma unroll
    for (int ds = 0; ds < 2; ++ds) {
        const float4* qp = (const float4*)(Qb + (size_t)(qb + qh*16 + n) * DD + ds*32 + quad*8);
        af[ds] = cvt8(qp[0], qp[1]);
    }
    float x2r[4];
#pragma unroll
    for (int r = 0; r < 4; ++r) x2r[r] = x2q[qh*16 + quad*4 + r];

    const int khbase = kh * (NK / KSPL / 2);      // 512-col half within block range
    float srow[4] = {0.f, 0.f, 0.f, 0.f};

    for (int kt0 = 0; kt0 < NK / KSPL / 2; kt0 += 64) {
        __syncthreads();
        // stage both 64-col k-halves: 1024 half8, 4/thread
#pragma unroll
        for (int i = 0; i < 4; ++i) {
            int s = t + i * 256;
            int h = s >> 9, f = (s >> 6) & 7, l = s & 63;
            int krow = kz + h * (NK / KSPL / 2) + kt0 + (f >> 1) * 16 + (l & 15);
            int dcol = (f & 1) * 32 + (l >> 4) * 8;
            const float4* kp = (const float4*)(Kb + (size_t)krow * DD + dcol);
            sB[h][f * 64 + l] = cvt8(kp[0], kp[1]);
        }
        __syncthreads();

        floatx4 acc[4] = {};
#pragma unroll
        for (int nt = 0; nt < 4; ++nt)
#pragma unroll
            for (int ds = 0; ds < 2; ++ds)
                acc[nt] = __builtin_amdgcn_mfma_f32_16x16x32_f16(
                    af[ds], sB[kh][(nt * 2 + ds) * 64 + lane], acc[nt], 0, 0, 0);

#pragma unroll
        for (int nt = 0; nt < 4; ++nt) {
            int lcol = khbase + kt0 + nt * 16 + n;
            float y2 = y2k[lcol];
#pragma unroll
            for (int r = 0; r < 4; ++r)
                srow[r] += score_exp(x2r[r], y2, acc[nt][r]);
        }
    }

    // reduce over the 16 col-lanes (n) within each quad group
#pragma unroll
    for (int off = 1; off < 16; off <<= 1)
#pragma unroll
        for (int r = 0; r < 4; ++r) srow[r] += __shfl_xor(srow[r], off);
    if (n == 0)
#pragma unroll
        for (int r = 0; r < 4; ++r) part[kh][qh * 16 + quad * 4 + r] = srow[r];
    __syncthreads();
    if (t < 32)
        RS[((size_t)blockIdx.z * BB + b) * NQ + qb + t] = part[0][t] + part[1][t];
}

// ---------------------------------------------------------------------------
// K3: recompute scores (same MFMA frags/order as K1 -> identical E), normalize
// with rcp(rowsum), single coalesced nontemporal W write, fp16 A-frags -> PV.
// E never touches HBM. Grid (NQ/32, BB), 256 thr = 4 waves.
// Wave roles: QK^T: (qh = w&1 q-half, kn = w>>1 k-32col-half);
//             PV:   (wq = w&1 q-half, wv = w>>1 v-64col-half).
// ---------------------------------------------------------------------------
__global__ __launch_bounds__(256)
void k3_fused(const float* __restrict__ Q, const float* __restrict__ Kp,
              const float* __restrict__ V, const float* __restrict__ RS,
              float* __restrict__ W, float* __restrict__ O)
{
    __shared__ half8 sB [8 * 64];       // K-tile frags (8 KB)
    __shared__ half8 sV [16 * 64];      // V-tile frags (16 KB)
    __shared__ half8 sEf[4 * 64];       // normalized W-tile A-frags (4 KB)
    __shared__ float sS[32][68];        // fp32 scores bounce tile (8.5 KB, padded)
    __shared__ float y2k[NK];           // 8 KB
    __shared__ float x2q[32];

    const int t = threadIdx.x, w = t >> 6, lane = t & 63;
    const int n = lane & 15, quad = lane >> 4;
    const int qh = w & 1, kn = w >> 1;
    const int b = blockIdx.y, qb = blockIdx.x * 32;

    const float* Kb = Kp + (size_t)b * NK * DD;
    const float* Qb = Q  + (size_t)b * NQ * DD;
    const float* Vb = V  + (size_t)b * NK * VV;

    // fp32 norms: all 2048 K rows (8/thread) + 32 Q rows  (identical code to K1)
#pragma unroll
    for (int j = 0; j < 8; ++j) {
        int row = t + j * 256;
        const float4* kr = (const float4*)(Kb + (size_t)row * DD);
        float s = 0.f;
#pragma unroll
        for (int i = 0; i < 16; ++i) {
            float4 v = kr[i];
            s = fmaf(v.x,v.x,s); s = fmaf(v.y,v.y,s);
            s = fmaf(v.z,v.z,s); s = fmaf(v.w,v.w,s);
        }
        y2k[row] = s;
    }
    if (t < 32) {
        const float4* qr = (const float4*)(Qb + (size_t)(qb + t) * DD);
        float s = 0.f;
#pragma unroll
        for (int i = 0; i < 16; ++i) {
            float4 v = qr[i];
            s = fmaf(v.x,v.x,s); s = fmaf(v.y,v.y,s);
            s = fmaf(v.z,v.z,s); s = fmaf(v.w,v.w,s);
        }
        x2q[t] = s;
    }
    __syncthreads();

    half8 af[2];
#pragma unroll
    for (int ds = 0; ds < 2; ++ds) {
        const float4* qp = (const float4*)(Qb + (size_t)(qb + qh*16 + n) * DD + ds*32 + quad*8);
        af[ds] = cvt8(qp[0], qp[1]);
    }
    float x2r[4];
#pragma unroll
    for (int r = 0; r < 4; ++r) x2r[r] = x2q[qh*16 + quad*4 + r];

    // per-thread normalize/W-write role: row erow, 8-col group ecg
    const int erow = t >> 3, ecg = (t & 7) * 8;
    const int eslot = ((erow >> 4) * 2 + (ecg >> 5)) * 64 + ((ecg & 31) >> 3) * 16 + (erow & 15);
    const float rsum = RS[(size_t)b * NQ + qb + erow]
                     + RS[((size_t)BB + b) * NQ + qb + erow];
    const float rl_my = __builtin_amdgcn_rcpf(rsum);

    float* Wb = W + (size_t)b * NQ * NK;
    float* Er = Wb + (size_t)(qb + erow) * NK;

    floatx4 acc[4] = {};

    for (int kt = 0; kt < NK; kt += 64) {
        __syncthreads();
        // stage K tile: 512 half8, 2/thread
#pragma unroll
        for (int i = 0; i < 2; ++i) {
            int s = t + i * 256, f = s >> 6, l = s & 63;
            int krow = kt + (f >> 1) * 16 + (l & 15);
            int dcol = (f & 1) * 32 + (l >> 4) * 8;
            const float4* kp = (const float4*)(Kb + (size_t)krow * DD + dcol);
            sB[f * 64 + l] = cvt8(kp[0], kp[1]);
        }
        // stage V tile 64k x 128v, frag-major (strided b32 loads, L2-hot)
#pragma unroll
        for (int i = 0; i < 4; ++i) {
            int sidx = t + i * 256, f = sidx >> 6, l = sidx & 63;
            const float* vp = Vb + (size_t)(kt + (f & 1) * 32 + (l >> 4) * 8) * VV
                                 + (f >> 1) * 16 + (l & 15);
            half8 h;
#pragma unroll
            for (int j = 0; j < 8; ++j) h[j] = (half_t)vp[j * VV];
            sV[f * 64 + l] = h;
        }
        __syncthreads();

        // QK^T: wave computes 16q x 32k; same frag values + accum order as K1
        floatx4 a2[2] = {};
#pragma unroll
        for (int nt = 0; nt < 2; ++nt)
#pragma unroll
            for (int ds = 0; ds < 2; ++ds)
                a2[nt] = __builtin_amdgcn_mfma_f32_16x16x32_f16(
                    af[ds], sB[((kn * 2 + nt) * 2 + ds) * 64 + lane], a2[nt], 0, 0, 0);

#pragma unroll
        for (int nt = 0; nt < 2; ++nt) {
            int col = kn * 32 + nt * 16 + n;
            float y2 = y2k[kt + col];
#pragma unroll
            for (int r = 0; r < 4; ++r)
                sS[qh * 16 + quad * 4 + r][col] = score_exp(x2r[r], y2, a2[nt][r]);
        }
        __syncthreads();

        // normalize -> W (nontemporal, coalesced float4) + fp16 A-frag
        float4 e0 = *(const float4*)&sS[erow][ecg];
        float4 e1 = *(const float4*)&sS[erow][ecg + 4];
        e0.x *= rl_my; e0.y *= rl_my; e0.z *= rl_my; e0.w *= rl_my;
        e1.x *= rl_my; e1.y *= rl_my; e1.z *= rl_my; e1.w *= rl_my;
        store_nt4(Er + kt + ecg,     e0);
        store_nt4(Er + kt + ecg + 4, e1);
        sEf[eslot] = cvt8(e0, e1);
        __syncthreads();

        // PV: A-frags pre-normalized -> acc IS the output
        half8 a0 = sEf[(qh * 2 + 0) * 64 + lane];
        half8 a1 = sEf[(qh * 2 + 1) * 64 + lane];
#pragma unroll
        for (int nt = 0; nt < 4; ++nt) {
            int fnt = kn * 4 + nt;
            acc[nt] = __builtin_amdgcn_mfma_f32_16x16x32_f16(
                a0, sV[(fnt * 2 + 0) * 64 + lane], acc[nt], 0, 0, 0);
            acc[nt] = __builtin_amdgcn_mfma_f32_16x16x32_f16(
                a1, sV[(fnt * 2 + 1) * 64 + lane], acc[nt], 0, 0, 0);
        }
    }

    float* Ob = O + (size_t)b * NQ * VV;
#pragma unroll
    for (int nt = 0; nt < 4; ++nt)
#pragma unroll
        for (int r = 0; r < 4; ++r)
            Ob[(size_t)(qb + qh * 16 + quad * 4 + r) * VV + kn * 64 + nt * 16 + n]
                = acc[nt][r];
}

// ---------------------------------------------------------------------------
extern "C" void kernel_launch(void* const* d_in, const int* in_sizes, int n_in,
                              void* d_out, int out_size, void* d_ws, size_t ws_size,
                              hipStream_t stream)
{
    const float* Q  = (const float*)d_in[0];
    const float* Kp = (const float*)d_in[1];
    const float* Vp = (const float*)d_in[2];

    float* O     = (float*)d_out;                 // (B, Nq, V)
    float* attnW = O + (size_t)BB * NQ * VV;      // (B, Nq, Nk) normalized W
    float* RS    = (float*)d_ws;                  // KSPL * B * NQ partial row sums

    k1_rowsum<<<dim3(NQ / 32, BB, KSPL), 256, 0, stream>>>(Q, Kp, RS);
    k3_fused <<<dim3(NQ / 32, BB),       256, 0, stream>>>(Q, Kp, Vp, RS, attnW, O);
}

// Round 3
// 261.632 us; speedup vs baseline: 1.3424x; 1.3424x over previous
//
#include <hip/hip_runtime.h>
#include <math.h>

#define BB 8
#define NQ 2048
#define NK 2048
#define DD 64
#define VV 128
#define EPSF 1e-7f
#define KSPL 2          // k-range split for k1 partial row sums
#define NT3 (NK / 64)   // 32 k-tiles
#define FIXROWS 1024    // W[b=0, rows<FIXROWS] is scratch during k0-k3; k4 rewrites

typedef _Float16 half_t;
typedef half_t half8 __attribute__((ext_vector_type(8)));
typedef float  floatx4 __attribute__((ext_vector_type(4)));

// exp(-arccosh(1+tt)^2); tt from fp32 norms + fp16-MFMA cross term.
// arccosh(1+tt) = ln(1+u), u = tt + sqrt(tt*(tt+2))   (bit-identical to prior rounds)
__device__ __forceinline__ float score_exp(float x2, float y2, float xy)
{
    float px = 1.f - x2, py = 1.f - y2;
    float sq = fmaxf(x2 + y2 - 2.f * xy, 0.f);
    float dn = fmaxf(px * py, EPSF);
    float tt = fmaxf(2.f * sq * __builtin_amdgcn_rcpf(dn), EPSF);
    float u  = tt + __builtin_amdgcn_sqrtf(fmaf(tt, tt, tt + tt));
    float d  = __logf(1.f + u);
    return __expf(-d * d);
}

__device__ __forceinline__ half8 cvt8(float4 a, float4 b)
{
    half8 h;
    h[0] = (half_t)a.x; h[1] = (half_t)a.y; h[2] = (half_t)a.z; h[3] = (half_t)a.w;
    h[4] = (half_t)b.x; h[5] = (half_t)b.y; h[6] = (half_t)b.z; h[7] = (half_t)b.w;
    return h;
}

// frag-major global layouts (half8 units), matching the LDS frag layouts
__device__ __forceinline__ size_t khg_idx(int b, int tile, int f, int l)
{ return (((size_t)b * NT3 + tile) * 8 + f) * 64 + l; }
__device__ __forceinline__ size_t vhg_idx(int b, int tile, int f, int l)
{ return (((size_t)b * NT3 + tile) * 16 + f) * 64 + l; }

// ---------------------------------------------------------------------------
// K0: one-time prep into scratch (carved from the W output region, b=0 rows
// < FIXROWS). fp16 K-frags (2MB) + V-frags (4MB) frag-major, plus y2/x2 row
// norms. Same cvt/fma chains as prior rounds -> downstream bit-identical.
// Grid (NK/64, BB).
// ---------------------------------------------------------------------------
__global__ __launch_bounds__(256)
void k0_prep(const float* __restrict__ Q, const float* __restrict__ Kp,
             const float* __restrict__ V, half8* __restrict__ Khg,
             half8* __restrict__ Vhg, float* __restrict__ y2g,
             float* __restrict__ x2g)
{
    const int t = threadIdx.x, b = blockIdx.y, tile = blockIdx.x;
    const int kt = tile * 64;
    const float* Kb = Kp + (size_t)b * NK * DD;
    const float* Qb = Q  + (size_t)b * NQ * DD;
    const float* Vb = V  + (size_t)b * NK * VV;

    // K frags: 2/thread (identical mapping + cvt8 as the old sB staging)
#pragma unroll
    for (int i = 0; i < 2; ++i) {
        int s = t + i * 256, f = s >> 6, l = s & 63;
        int krow = kt + (f >> 1) * 16 + (l & 15);
        int dcol = (f & 1) * 32 + (l >> 4) * 8;
        const float4* kp = (const float4*)(Kb + (size_t)krow * DD + dcol);
        Khg[khg_idx(b, tile, f, l)] = cvt8(kp[0], kp[1]);
    }
    // V frags: 4/thread (identical mapping + cvt as the old sV staging)
#pragma unroll
    for (int i = 0; i < 4; ++i) {
        int s = t + i * 256, f = s >> 6, l = s & 63;
        const float* vp = Vb + (size_t)(kt + (f & 1) * 32 + (l >> 4) * 8) * VV
                             + (f >> 1) * 16 + (l & 15);
        half8 h;
#pragma unroll
        for (int j = 0; j < 8; ++j) h[j] = (half_t)vp[j * VV];
        Vhg[vhg_idx(b, tile, f, l)] = h;
    }
    // norms (same fmaf chain as before -> bit-identical)
    if (t < 64) {
        const float4* kr = (const float4*)(Kb + (size_t)(kt + t) * DD);
        float s = 0.f;
#pragma unroll
        for (int i = 0; i < 16; ++i) {
            float4 v = kr[i];
            s = fmaf(v.x,v.x,s); s = fmaf(v.y,v.y,s);
            s = fmaf(v.z,v.z,s); s = fmaf(v.w,v.w,s);
        }
        y2g[(size_t)b * NK + kt + t] = s;
    } else if (t < 128) {
        int r = t - 64;
        const float4* qr = (const float4*)(Qb + (size_t)(kt + r) * DD);
        float s = 0.f;
#pragma unroll
        for (int i = 0; i < 16; ++i) {
            float4 v = qr[i];
            s = fmaf(v.x,v.x,s); s = fmaf(v.y,v.y,s);
            s = fmaf(v.z,v.z,s); s = fmaf(v.w,v.w,s);
        }
        x2g[(size_t)b * NQ + kt + r] = s;
    }
}

// ---------------------------------------------------------------------------
// K1: row sums of E over this block's NK/KSPL k-range, from precomputed frags.
// Reg-prefetch of next tile hides L2 latency. Same MFMA/score/accumulate
// order as the passing round-1 kernel. Grid (NQ/32, BB, KSPL).
// ---------------------------------------------------------------------------
__global__ __launch_bounds__(256)
void k1_rowsum(const float* __restrict__ Q, const half8* __restrict__ Khg,
               const float* __restrict__ y2g, const float* __restrict__ x2g,
               float* __restrict__ RS)
{
    __shared__ half8 sB[2][8 * 64];          // [k-half][frag*64+lane]
    __shared__ float y2k[NK / KSPL];
    __shared__ float part[2][32];

    const int t = threadIdx.x, w = t >> 6, lane = t & 63;
    const int n = lane & 15, quad = lane >> 4;
    const int qh = w & 1, kh = w >> 1;
    const int b = blockIdx.y, qb = blockIdx.x * 32;
    const int kz = blockIdx.z * (NK / KSPL);
    const int tbase = blockIdx.z * 16;       // first tile index of this k-range

    const float* Qb = Q + (size_t)b * NQ * DD;

    // y2 block (4 floats/thread, coalesced)
    ((float4*)y2k)[t] = ((const float4*)(y2g + (size_t)b * NK + kz))[t];

    half8 af[2];
#pragma unroll
    for (int ds = 0; ds < 2; ++ds) {
        const float4* qp = (const float4*)(Qb + (size_t)(qb + qh*16 + n) * DD + ds*32 + quad*8);
        af[ds] = cvt8(qp[0], qp[1]);
    }
    float x2r[4];
#pragma unroll
    for (int r = 0; r < 4; ++r)
        x2r[r] = x2g[(size_t)b * NQ + qb + qh*16 + quad*4 + r];

    // prologue: stage tile kt0=0 (both kh halves)
    {
        half8 pk[4];
#pragma unroll
        for (int i = 0; i < 4; ++i) {
            int s = t + i * 256, h = s >> 9, f = (s >> 6) & 7, l = s & 63;
            pk[i] = Khg[khg_idx(b, tbase + h * 8, f, l)];
        }
#pragma unroll
        for (int i = 0; i < 4; ++i) {
            int s = t + i * 256, h = s >> 9, f = (s >> 6) & 7, l = s & 63;
            sB[h][f * 64 + l] = pk[i];
        }
    }
    __syncthreads();

    const int khbase = kh * (NK / KSPL / 2);
    float srow[4] = {0.f, 0.f, 0.f, 0.f};

#pragma unroll 1
    for (int kt0 = 0; kt0 < NK / KSPL / 2; kt0 += 64) {
        const bool pf = (kt0 + 64) < (NK / KSPL / 2);
        half8 pk[4];
        if (pf) {
#pragma unroll
            for (int i = 0; i < 4; ++i) {
                int s = t + i * 256, h = s >> 9, f = (s >> 6) & 7, l = s & 63;
                pk[i] = Khg[khg_idx(b, tbase + h * 8 + ((kt0 + 64) >> 6), f, l)];
            }
        }

        floatx4 acc[4] = {};
#pragma unroll
        for (int nt = 0; nt < 4; ++nt)
#pragma unroll
            for (int ds = 0; ds < 2; ++ds)
                acc[nt] = __builtin_amdgcn_mfma_f32_16x16x32_f16(
                    af[ds], sB[kh][(nt * 2 + ds) * 64 + lane], acc[nt], 0, 0, 0);

#pragma unroll
        for (int nt = 0; nt < 4; ++nt) {
            int lcol = khbase + kt0 + nt * 16 + n;
            float y2 = y2k[lcol];
#pragma unroll
            for (int r = 0; r < 4; ++r)
                srow[r] += score_exp(x2r[r], y2, acc[nt][r]);
        }
        __syncthreads();                 // all waves done reading sB
        if (pf) {
#pragma unroll
            for (int i = 0; i < 4; ++i) {
                int s = t + i * 256, h = s >> 9, f = (s >> 6) & 7, l = s & 63;
                sB[h][f * 64 + l] = pk[i];
            }
        }
        __syncthreads();
    }

    // reduce over the 16 col-lanes (n)
#pragma unroll
    for (int off = 1; off < 16; off <<= 1)
#pragma unroll
        for (int r = 0; r < 4; ++r) srow[r] += __shfl_xor(srow[r], off);
    if (n == 0)
#pragma unroll
        for (int r = 0; r < 4; ++r) part[kh][qh * 16 + quad * 4 + r] = srow[r];
    __syncthreads();
    if (t < 32)
        RS[((size_t)blockIdx.z * BB + b) * NQ + qb + t] = part[0][t] + part[1][t];
}

// ---------------------------------------------------------------------------
// K3: fused scores+normalize+W-store+PV from precomputed frags, 2-phase
// reg-prefetch pipeline, 2 barriers/tile. W stored directly from score regs
// (nt, 64B segments); PV A-frags read from sS. Blocks whose W rows hold the
// frag scratch (b==0 && qb<FIXROWS) skip W stores; k4 rewrites those rows.
// Grid: flat 512 blocks, XCD-swizzled so each XCD owns one batch b.
// ---------------------------------------------------------------------------
__global__ __launch_bounds__(256)
void k3_fused(const float* __restrict__ Q, const half8* __restrict__ Khg,
              const half8* __restrict__ Vhg, const float* __restrict__ y2g,
              const float* __restrict__ x2g, const float* __restrict__ RS,
              float* __restrict__ W, float* __restrict__ O)
{
    __shared__ half8 sB[2][8 * 64];      // 2 x 8KB  K frags (dbuf)
    __shared__ half8 sV[2][16 * 64];     // 2 x 16KB V frags (dbuf)
    __shared__ float sS[32][68];         // 8.5KB normalized scores bounce
    __shared__ float y2k[NK];            // 8KB

    const int t = threadIdx.x, w = t >> 6, lane = t & 63;
    const int n = lane & 15, quad = lane >> 4;
    const int qh = w & 1, kn = w >> 1;

    // XCD swizzle: 512 blocks, 8 XCDs -> XCD i handles batch b=i entirely
    const int bid = blockIdx.x;
    const int swz = (bid & 7) * 64 + (bid >> 3);
    const int b = swz >> 6, qb = (swz & 63) * 32;
    const bool wskip = (b == 0) && (qb < FIXROWS);   // scratch rows: k4 rewrites

    const float* Qb = Q + (size_t)b * NQ * DD;

    // y2 full row set (2 float4/thread)
#pragma unroll
    for (int i = 0; i < 2; ++i)
        ((float4*)y2k)[t + i * 256] = ((const float4*)(y2g + (size_t)b * NK))[t + i * 256];

    half8 af[2];
#pragma unroll
    for (int ds = 0; ds < 2; ++ds) {
        const float4* qp = (const float4*)(Qb + (size_t)(qb + qh*16 + n) * DD + ds*32 + quad*8);
        af[ds] = cvt8(qp[0], qp[1]);
    }
    float x2r[4], rlr[4];
#pragma unroll
    for (int r = 0; r < 4; ++r) {
        int row = qb + qh * 16 + quad * 4 + r;
        x2r[r] = x2g[(size_t)b * NQ + row];
        float rsum = RS[(size_t)b * NQ + row] + RS[((size_t)BB + b) * NQ + row];
        rlr[r] = __builtin_amdgcn_rcpf(rsum);
    }

    // prologue: stage tile 0 into buf 0
    {
        half8 rk[2], rv[4];
#pragma unroll
        for (int i = 0; i < 2; ++i) { int s=t+i*256, f=s>>6, l=s&63; rk[i] = Khg[khg_idx(b,0,f,l)]; }
#pragma unroll
        for (int i = 0; i < 4; ++i) { int s=t+i*256, f=s>>6, l=s&63; rv[i] = Vhg[vhg_idx(b,0,f,l)]; }
#pragma unroll
        for (int i = 0; i < 2; ++i) { int s=t+i*256, f=s>>6, l=s&63; sB[0][f*64+l] = rk[i]; }
#pragma unroll
        for (int i = 0; i < 4; ++i) { int s=t+i*256, f=s>>6, l=s&63; sV[0][f*64+l] = rv[i]; }
    }
    __syncthreads();

    float* Wb = W + (size_t)b * NQ * NK;
    floatx4 acc[4] = {};

#pragma unroll 1
    for (int tt = 0; tt < NT3; ++tt) {
        const int cur = tt & 1;
        half8* sBc = (half8*)sB[cur];
        half8* sVc = (half8*)sV[cur];
        const bool pf = (tt + 1) < NT3;

        // A) prefetch next tile to regs (latency hides under B+C)
        half8 rk[2], rv[4];
        if (pf) {
#pragma unroll
            for (int i = 0; i < 2; ++i) { int s=t+i*256, f=s>>6, l=s&63; rk[i] = Khg[khg_idx(b,tt+1,f,l)]; }
#pragma unroll
            for (int i = 0; i < 4; ++i) { int s=t+i*256, f=s>>6, l=s&63; rv[i] = Vhg[vhg_idx(b,tt+1,f,l)]; }
        }

        // B) QK^T: wave (qh,kn) -> 16q x 32k  (same frag values + accum order)
        floatx4 a2[2] = {};
#pragma unroll
        for (int nt = 0; nt < 2; ++nt)
#pragma unroll
            for (int ds = 0; ds < 2; ++ds)
                a2[nt] = __builtin_amdgcn_mfma_f32_16x16x32_f16(
                    af[ds], sBc[((kn * 2 + nt) * 2 + ds) * 64 + lane], a2[nt], 0, 0, 0);

        // C) scores -> normalized W (direct nt store, 64B segments) + sS
#pragma unroll
        for (int nt = 0; nt < 2; ++nt) {
            int col = kn * 32 + nt * 16 + n;
            int gcol = tt * 64 + col;
            float y2 = y2k[gcol];
#pragma unroll
            for (int r = 0; r < 4; ++r) {
                float e  = score_exp(x2r[r], y2, a2[nt][r]);
                float wv = e * rlr[r];
                int row = qh * 16 + quad * 4 + r;
                if (!wskip)
                    __builtin_nontemporal_store(wv, Wb + (size_t)(qb + row) * NK + gcol);
                sS[row][col] = wv;
            }
        }
        __syncthreads();   // sS visible

        // D) PV: A-frags straight from sS (pre-normalized -> acc IS output)
        const float* sp0 = &sS[qh * 16 + n][quad * 8];
        float4 p00 = *(const float4*)(sp0);
        float4 p01 = *(const float4*)(sp0 + 4);
        float4 p10 = *(const float4*)(sp0 + 32);
        float4 p11 = *(const float4*)(sp0 + 36);
        half8 a0 = cvt8(p00, p01);
        half8 a1 = cvt8(p10, p11);
#pragma unroll
        for (int nt = 0; nt < 4; ++nt) {
            int fnt = kn * 4 + nt;
            acc[nt] = __builtin_amdgcn_mfma_f32_16x16x32_f16(
                a0, sVc[(fnt * 2 + 0) * 64 + lane], acc[nt], 0, 0, 0);
            acc[nt] = __builtin_amdgcn_mfma_f32_16x16x32_f16(
                a1, sVc[(fnt * 2 + 1) * 64 + lane], acc[nt], 0, 0, 0);
        }

        // E) write prefetched tile into the other buffer
        if (pf) {
            half8* sBn = (half8*)sB[cur ^ 1];
            half8* sVn = (half8*)sV[cur ^ 1];
#pragma unroll
            for (int i = 0; i < 2; ++i) { int s=t+i*256, f=s>>6, l=s&63; sBn[f*64+l] = rk[i]; }
#pragma unroll
            for (int i = 0; i < 4; ++i) { int s=t+i*256, f=s>>6, l=s&63; sVn[f*64+l] = rv[i]; }
        }
        __syncthreads();   // buf^1 + sS reuse protected
    }

    float* Ob = O + (size_t)b * NQ * VV;
#pragma unroll
    for (int nt = 0; nt < 4; ++nt)
#pragma unroll
        for (int r = 0; r < 4; ++r)
            Ob[(size_t)(qb + qh * 16 + quad * 4 + r) * VV + kn * 64 + nt * 16 + n]
                = acc[nt][r];
}

// ---------------------------------------------------------------------------
// K4: rewrite W[b=0, rows<FIXROWS] (the scratch region) AFTER k3. Reads ONLY
// raw Q/K + RS (d_ws) -- never the frags it is overwriting. Identical value
// pipeline (cvt8 staging, MFMA order, score_exp, e*rl) -> same W as k3 would
// have stored. Grid (FIXROWS/32, 4 k-splits).
// ---------------------------------------------------------------------------
__global__ __launch_bounds__(256)
void k4_wfix(const float* __restrict__ Q, const float* __restrict__ Kp,
             const float* __restrict__ RS, float* __restrict__ W)
{
    __shared__ half8 sB[8 * 64];
    __shared__ float y2k[512];
    __shared__ float x2q[32];

    const int t = threadIdx.x, w = t >> 6, lane = t & 63;
    const int n = lane & 15, quad = lane >> 4;
    const int qh = w & 1, kn = w >> 1;
    const int qb = blockIdx.x * 32;          // batch 0 rows
    const int kz = blockIdx.y * 512;

    // K norms for this 512-col range (same fmaf chain) + 32 Q norms
#pragma unroll
    for (int j = 0; j < 2; ++j) {
        int row = t + j * 256;
        const float4* kr = (const float4*)(Kp + (size_t)(kz + row) * DD);
        float s = 0.f;
#pragma unroll
        for (int i = 0; i < 16; ++i) {
            float4 v = kr[i];
            s = fmaf(v.x,v.x,s); s = fmaf(v.y,v.y,s);
            s = fmaf(v.z,v.z,s); s = fmaf(v.w,v.w,s);
        }
        y2k[row] = s;
    }
    if (t < 32) {
        const float4* qr = (const float4*)(Q + (size_t)(qb + t) * DD);
        float s = 0.f;
#pragma unroll
        for (int i = 0; i < 16; ++i) {
            float4 v = qr[i];
            s = fmaf(v.x,v.x,s); s = fmaf(v.y,v.y,s);
            s = fmaf(v.z,v.z,s); s = fmaf(v.w,v.w,s);
        }
        x2q[t] = s;
    }
    __syncthreads();

    half8 af[2];
#pragma unroll
    for (int ds = 0; ds < 2; ++ds) {
        const float4* qp = (const float4*)(Q + (size_t)(qb + qh*16 + n) * DD + ds*32 + quad*8);
        af[ds] = cvt8(qp[0], qp[1]);
    }
    float x2r[4], rlr[4];
#pragma unroll
    for (int r = 0; r < 4; ++r) {
        int row = qb + qh * 16 + quad * 4 + r;
        x2r[r] = x2q[qh * 16 + quad * 4 + r];
        rlr[r] = __builtin_amdgcn_rcpf(RS[row] + RS[(size_t)BB * NQ + row]);
    }

#pragma unroll 1
    for (int kt = 0; kt < 512; kt += 64) {
        __syncthreads();
        // stage K tile raw -> fp16 frags (identical mapping + cvt8)
#pragma unroll
        for (int i = 0; i < 2; ++i) {
            int s = t + i * 256, f = s >> 6, l = s & 63;
            int krow = kz + kt + (f >> 1) * 16 + (l & 15);
            int dcol = (f & 1) * 32 + (l >> 4) * 8;
            const float4* kp = (const float4*)(Kp + (size_t)krow * DD + dcol);
            sB[f * 64 + l] = cvt8(kp[0], kp[1]);
        }
        __syncthreads();

        floatx4 a2[2] = {};
#pragma unroll
        for (int nt = 0; nt < 2; ++nt)
#pragma unroll
            for (int ds = 0; ds < 2; ++ds)
                a2[nt] = __builtin_amdgcn_mfma_f32_16x16x32_f16(
                    af[ds], sB[((kn * 2 + nt) * 2 + ds) * 64 + lane], a2[nt], 0, 0, 0);

#pragma unroll
        for (int nt = 0; nt < 2; ++nt) {
            int col = kn * 32 + nt * 16 + n;
            float y2 = y2k[kt + col];
#pragma unroll
            for (int r = 0; r < 4; ++r) {
                float e = score_exp(x2r[r], y2, a2[nt][r]);
                int row = qh * 16 + quad * 4 + r;
                W[(size_t)(qb + row) * NK + kz + kt + col] = e * rlr[r];
            }
        }
    }
}

// ---------------------------------------------------------------------------
extern "C" void kernel_launch(void* const* d_in, const int* in_sizes, int n_in,
                              void* d_out, int out_size, void* d_ws, size_t ws_size,
                              hipStream_t stream)
{
    const float* Q  = (const float*)d_in[0];
    const float* Kp = (const float*)d_in[1];
    const float* Vp = (const float*)d_in[2];

    float* O     = (float*)d_out;                 // (B, Nq, V)
    float* attnW = O + (size_t)BB * NQ * VV;      // (B, Nq, Nk) normalized W

    // scratch carved from W[b=0, rows<FIXROWS] (8 MB; we use 6.42 MB):
    //   Khg (2MB) | Vhg (4MB) | y2 (64KB) | x2 (64KB). k4 rewrites these rows.
    half8* Khg = (half8*)attnW;
    half8* Vhg = Khg + (size_t)BB * NT3 * 8 * 64;
    float* y2g = (float*)(Vhg + (size_t)BB * NT3 * 16 * 64);
    float* x2g = y2g + (size_t)BB * NK;

    // d_ws: only RS (128 KB -- the size proven safe in round 1)
    float* RS = (float*)d_ws;                     // KSPL * B * NQ floats

    k0_prep  <<<dim3(NK / 64, BB),       256, 0, stream>>>(Q, Kp, Vp, Khg, Vhg, y2g, x2g);
    k1_rowsum<<<dim3(NQ / 32, BB, KSPL), 256, 0, stream>>>(Q, Khg, y2g, x2g, RS);
    k3_fused <<<dim3(BB * (NQ / 32)),    256, 0, stream>>>(Q, Khg, Vhg, y2g, x2g, RS, attnW, O);
    k4_wfix  <<<dim3(FIXROWS / 32, 4),   256, 0, stream>>>(Q, Kp, RS, attnW);
}

// Round 5
// 260.032 us; speedup vs baseline: 1.3507x; 1.0062x over previous
//
#include <hip/hip_runtime.h>
#include <math.h>

#define BB 8
#define NQ 2048
#define NK 2048
#define DD 64
#define VV 128
#define EPSF 1e-7f
#define NT3 (NK / 64)   // 32 k-tiles
#define FIXROWS 1024    // W[b=0, rows<FIXROWS] is scratch during k0-k_main; k4 rewrites

typedef _Float16 half_t;
typedef half_t half8 __attribute__((ext_vector_type(8)));
typedef float  floatx4 __attribute__((ext_vector_type(4)));

// exp(-arccosh(1+tt)^2); tt from fp32 norms + fp16-MFMA cross term.
// arccosh(1+tt) = ln(1+u), u = tt + sqrt(tt*(tt+2))   (bit-identical to prior rounds)
__device__ __forceinline__ float score_exp(float x2, float y2, float xy)
{
    float px = 1.f - x2, py = 1.f - y2;
    float sq = fmaxf(x2 + y2 - 2.f * xy, 0.f);
    float dn = fmaxf(px * py, EPSF);
    float tt = fmaxf(2.f * sq * __builtin_amdgcn_rcpf(dn), EPSF);
    float u  = tt + __builtin_amdgcn_sqrtf(fmaf(tt, tt, tt + tt));
    float d  = __logf(1.f + u);
    return __expf(-d * d);
}

__device__ __forceinline__ half8 cvt8(float4 a, float4 b)
{
    half8 h;
    h[0] = (half_t)a.x; h[1] = (half_t)a.y; h[2] = (half_t)a.z; h[3] = (half_t)a.w;
    h[4] = (half_t)b.x; h[5] = (half_t)b.y; h[6] = (half_t)b.z; h[7] = (half_t)b.w;
    return h;
}

// frag-major global layouts (half8 units), matching the LDS frag layouts
__device__ __forceinline__ size_t khg_idx(int b, int tile, int f, int l)
{ return (((size_t)b * NT3 + tile) * 8 + f) * 64 + l; }
__device__ __forceinline__ size_t vhg_idx(int b, int tile, int f, int l)
{ return (((size_t)b * NT3 + tile) * 16 + f) * 64 + l; }

// ---------------------------------------------------------------------------
// K0: one-time prep into scratch (carved from the W output region, b=0 rows
// < FIXROWS). fp16 K-frags (2MB) + V-frags (4MB) frag-major, plus y2/x2 row
// norms. Same cvt/fma chains as prior rounds -> downstream bit-identical.
// Grid (NK/64, BB).   [PROVEN round 3]
// ---------------------------------------------------------------------------
__global__ __launch_bounds__(256)
void k0_prep(const float* __restrict__ Q, const float* __restrict__ Kp,
             const float* __restrict__ V, half8* __restrict__ Khg,
             half8* __restrict__ Vhg, float* __restrict__ y2g,
             float* __restrict__ x2g)
{
    const int t = threadIdx.x, b = blockIdx.y, tile = blockIdx.x;
    const int kt = tile * 64;
    const float* Kb = Kp + (size_t)b * NK * DD;
    const float* Qb = Q  + (size_t)b * NQ * DD;
    const float* Vb = V  + (size_t)b * NK * VV;

#pragma unroll
    for (int i = 0; i < 2; ++i) {
        int s = t + i * 256, f = s >> 6, l = s & 63;
        int krow = kt + (f >> 1) * 16 + (l & 15);
        int dcol = (f & 1) * 32 + (l >> 4) * 8;
        const float4* kp = (const float4*)(Kb + (size_t)krow * DD + dcol);
        Khg[khg_idx(b, tile, f, l)] = cvt8(kp[0], kp[1]);
    }
#pragma unroll
    for (int i = 0; i < 4; ++i) {
        int s = t + i * 256, f = s >> 6, l = s & 63;
        const float* vp = Vb + (size_t)(kt + (f & 1) * 32 + (l >> 4) * 8) * VV
                             + (f >> 1) * 16 + (l & 15);
        half8 h;
#pragma unroll
        for (int j = 0; j < 8; ++j) h[j] = (half_t)vp[j * VV];
        Vhg[vhg_idx(b, tile, f, l)] = h;
    }
    if (t < 64) {
        const float4* kr = (const float4*)(Kb + (size_t)(kt + t) * DD);
        float s = 0.f;
#pragma unroll
        for (int i = 0; i < 16; ++i) {
            float4 v = kr[i];
            s = fmaf(v.x,v.x,s); s = fmaf(v.y,v.y,s);
            s = fmaf(v.z,v.z,s); s = fmaf(v.w,v.w,s);
        }
        y2g[(size_t)b * NK + kt + t] = s;
    } else if (t < 128) {
        int r = t - 64;
        const float4* qr = (const float4*)(Qb + (size_t)(kt + r) * DD);
        float s = 0.f;
#pragma unroll
        for (int i = 0; i < 16; ++i) {
            float4 v = qr[i];
            s = fmaf(v.x,v.x,s); s = fmaf(v.y,v.y,s);
            s = fmaf(v.z,v.z,s); s = fmaf(v.w,v.w,s);
        }
        x2g[(size_t)b * NQ + kt + r] = s;
    }
}

// ---------------------------------------------------------------------------
// K_MAIN = round-3 k1 + k3 fused, both sweeps verbatim-proven.
// Sweep 1: rowsum over all 2048 k (k1 structure, KSPL=1: wave (qh,kh) sweeps
//          kh's 1024-col half) -> rsumS (LDS) + RS (global, for k4).
// Sweep 2: round-3 k3 loop verbatim: QK^T -> wv = e*rlr -> normalized W store
//          (nt) + sS -> PV MFMA -> O = acc directly.
// Grid: flat 512 blocks, XCD-swizzled so each XCD owns one batch b.
// ---------------------------------------------------------------------------
__global__ __launch_bounds__(256)
void k_main(const float* __restrict__ Q, const half8* __restrict__ Khg,
            const half8* __restrict__ Vhg, const float* __restrict__ y2g,
            const float* __restrict__ x2g, float* __restrict__ W,
            float* __restrict__ O, float* __restrict__ RS)
{
    __shared__ half8 sB[2][8 * 64];      // sweep1: [kh-half]; sweep2: dbuf (16KB)
    __shared__ half8 sV[2][16 * 64];     // sweep2 V frags dbuf (32KB)
    __shared__ float sS[32][68];         // normalized scores bounce (8.5KB)
    __shared__ float y2k[NK];            // 8KB
    __shared__ float part[2][32];        // rowsum cross-wave reduce
    __shared__ float rsumS[32];          // final row sums

    const int t = threadIdx.x, w = t >> 6, lane = t & 63;
    const int n = lane & 15, quad = lane >> 4;
    const int qh = w & 1, kh = w >> 1;   // kh: sweep1 1024-half / sweep2 V-half

    // XCD swizzle: 512 blocks, 8 XCDs -> XCD i handles batch b=i entirely
    const int bid = blockIdx.x;
    const int swz = (bid & 7) * 64 + (bid >> 3);
    const int b = swz >> 6, qb = (swz & 63) * 32;
    const bool wskip = (b == 0) && (qb < FIXROWS);   // scratch rows: k4 rewrites

    const float* Qb = Q + (size_t)b * NQ * DD;

    // y2 full row set (2 float4/thread)
#pragma unroll
    for (int i = 0; i < 2; ++i)
        ((float4*)y2k)[t + i * 256] = ((const float4*)(y2g + (size_t)b * NK))[t + i * 256];

    half8 af[2];
#pragma unroll
    for (int ds = 0; ds < 2; ++ds) {
        const float4* qp = (const float4*)(Qb + (size_t)(qb + qh*16 + n) * DD + ds*32 + quad*8);
        af[ds] = cvt8(qp[0], qp[1]);
    }
    float x2r[4];
#pragma unroll
    for (int r = 0; r < 4; ++r)
        x2r[r] = x2g[(size_t)b * NQ + qb + qh * 16 + quad * 4 + r];

    // ======================= sweep 1: row sums (k1, KSPL=1) =================
    {
        half8 pk[4];
#pragma unroll
        for (int i = 0; i < 4; ++i) {
            int s = t + i * 256, h = s >> 9, f = (s >> 6) & 7, l = s & 63;
            pk[i] = Khg[khg_idx(b, h * 16, f, l)];
        }
#pragma unroll
        for (int i = 0; i < 4; ++i) {
            int s = t + i * 256, h = s >> 9, f = (s >> 6) & 7, l = s & 63;
            sB[h][f * 64 + l] = pk[i];
        }
    }
    __syncthreads();

    const int khbase = kh * 1024;
    float srow[4] = {0.f, 0.f, 0.f, 0.f};

#pragma unroll 1
    for (int kt0 = 0; kt0 < 1024; kt0 += 64) {
        const bool pf = (kt0 + 64) < 1024;
        half8 pk[4];
        if (pf) {
#pragma unroll
            for (int i = 0; i < 4; ++i) {
                int s = t + i * 256, h = s >> 9, f = (s >> 6) & 7, l = s & 63;
                pk[i] = Khg[khg_idx(b, h * 16 + ((kt0 + 64) >> 6), f, l)];
            }
        }

        floatx4 acc4[4] = {};
#pragma unroll
        for (int nt = 0; nt < 4; ++nt)
#pragma unroll
            for (int ds = 0; ds < 2; ++ds)
                acc4[nt] = __builtin_amdgcn_mfma_f32_16x16x32_f16(
                    af[ds], sB[kh][(nt * 2 + ds) * 64 + lane], acc4[nt], 0, 0, 0);

#pragma unroll
        for (int nt = 0; nt < 4; ++nt) {
            int lcol = khbase + kt0 + nt * 16 + n;
            float y2 = y2k[lcol];
#pragma unroll
            for (int r = 0; r < 4; ++r)
                srow[r] += score_exp(x2r[r], y2, acc4[nt][r]);
        }
        __syncthreads();                 // all waves done reading sB
        if (pf) {
#pragma unroll
            for (int i = 0; i < 4; ++i) {
                int s = t + i * 256, h = s >> 9, f = (s >> 6) & 7, l = s & 63;
                sB[h][f * 64 + l] = pk[i];
            }
        }
        __syncthreads();
    }

    // reduce over the 16 col-lanes (n)  [k1-verbatim, proven]
#pragma unroll
    for (int off = 1; off < 16; off <<= 1)
#pragma unroll
        for (int r = 0; r < 4; ++r) srow[r] += __shfl_xor(srow[r], off);
    if (n == 0)
#pragma unroll
        for (int r = 0; r < 4; ++r) part[kh][qh * 16 + quad * 4 + r] = srow[r];
    __syncthreads();
    if (t < 32) {
        float s = part[0][t] + part[1][t];
        RS[(size_t)b * NQ + qb + t] = s;    // for k4
        rsumS[t] = s;
    }
    __syncthreads();

    float rlr[4];
#pragma unroll
    for (int r = 0; r < 4; ++r)
        rlr[r] = __builtin_amdgcn_rcpf(rsumS[qh * 16 + quad * 4 + r]);

    // ======================= sweep 2: k3 round-3 verbatim ===================
    {
        half8 rk[2], rv[4];
#pragma unroll
        for (int i = 0; i < 2; ++i) { int s=t+i*256, f=s>>6, l=s&63; rk[i] = Khg[khg_idx(b,0,f,l)]; }
#pragma unroll
        for (int i = 0; i < 4; ++i) { int s=t+i*256, f=s>>6, l=s&63; rv[i] = Vhg[vhg_idx(b,0,f,l)]; }
#pragma unroll
        for (int i = 0; i < 2; ++i) { int s=t+i*256, f=s>>6, l=s&63; sB[0][f*64+l] = rk[i]; }
#pragma unroll
        for (int i = 0; i < 4; ++i) { int s=t+i*256, f=s>>6, l=s&63; sV[0][f*64+l] = rv[i]; }
    }
    __syncthreads();

    float* Wb = W + (size_t)b * NQ * NK;
    floatx4 acc[4] = {};

#pragma unroll 1
    for (int tt = 0; tt < NT3; ++tt) {
        const int cur = tt & 1;
        half8* sBc = (half8*)sB[cur];
        half8* sVc = (half8*)sV[cur];
        const bool pf = (tt + 1) < NT3;

        // A) prefetch next tile to regs (latency hides under B+C)
        half8 rk[2], rv[4];
        if (pf) {
#pragma unroll
            for (int i = 0; i < 2; ++i) { int s=t+i*256, f=s>>6, l=s&63; rk[i] = Khg[khg_idx(b,tt+1,f,l)]; }
#pragma unroll
            for (int i = 0; i < 4; ++i) { int s=t+i*256, f=s>>6, l=s&63; rv[i] = Vhg[vhg_idx(b,tt+1,f,l)]; }
        }

        // B) QK^T: wave (qh,kh) -> 16q x 32k (same frag values + accum order)
        floatx4 a2[2] = {};
#pragma unroll
        for (int nt = 0; nt < 2; ++nt)
#pragma unroll
            for (int ds = 0; ds < 2; ++ds)
                a2[nt] = __builtin_amdgcn_mfma_f32_16x16x32_f16(
                    af[ds], sBc[((kh * 2 + nt) * 2 + ds) * 64 + lane], a2[nt], 0, 0, 0);

        // C) scores -> normalized W (direct nt store, 64B segments) + sS
#pragma unroll
        for (int nt = 0; nt < 2; ++nt) {
            int col = kh * 32 + nt * 16 + n;
            int gcol = tt * 64 + col;
            float y2 = y2k[gcol];
#pragma unroll
            for (int r = 0; r < 4; ++r) {
                float e  = score_exp(x2r[r], y2, a2[nt][r]);
                float wv = e * rlr[r];
                int row = qh * 16 + quad * 4 + r;
                if (!wskip)
                    __builtin_nontemporal_store(wv, Wb + (size_t)(qb + row) * NK + gcol);
                sS[row][col] = wv;
            }
        }
        __syncthreads();   // sS visible

        // D) PV: A-frags straight from sS (pre-normalized -> acc IS output)
        const float* sp0 = &sS[qh * 16 + n][quad * 8];
        float4 p00 = *(const float4*)(sp0);
        float4 p01 = *(const float4*)(sp0 + 4);
        float4 p10 = *(const float4*)(sp0 + 32);
        float4 p11 = *(const float4*)(sp0 + 36);
        half8 a0 = cvt8(p00, p01);
        half8 a1 = cvt8(p10, p11);
#pragma unroll
        for (int nt = 0; nt < 4; ++nt) {
            int fnt = kh * 4 + nt;
            acc[nt] = __builtin_amdgcn_mfma_f32_16x16x32_f16(
                a0, sVc[(fnt * 2 + 0) * 64 + lane], acc[nt], 0, 0, 0);
            acc[nt] = __builtin_amdgcn_mfma_f32_16x16x32_f16(
                a1, sVc[(fnt * 2 + 1) * 64 + lane], acc[nt], 0, 0, 0);
        }

        // E) write prefetched tile into the other buffer
        if (pf) {
            half8* sBn = (half8*)sB[cur ^ 1];
            half8* sVn = (half8*)sV[cur ^ 1];
#pragma unroll
            for (int i = 0; i < 2; ++i) { int s=t+i*256, f=s>>6, l=s&63; sBn[f*64+l] = rk[i]; }
#pragma unroll
            for (int i = 0; i < 4; ++i) { int s=t+i*256, f=s>>6, l=s&63; sVn[f*64+l] = rv[i]; }
        }
        __syncthreads();   // buf^1 + sS reuse protected
    }

    // A-frags were pre-normalized -> acc IS the output  [round-3 proven]
    float* Ob = O + (size_t)b * NQ * VV;
#pragma unroll
    for (int nt = 0; nt < 4; ++nt)
#pragma unroll
        for (int r = 0; r < 4; ++r)
            Ob[(size_t)(qb + qh * 16 + quad * 4 + r) * VV + kh * 64 + nt * 16 + n]
                = acc[nt][r];
}

// ---------------------------------------------------------------------------
// K4: rewrite W[b=0, rows<FIXROWS] (the scratch region) AFTER k_main. Reads
// ONLY raw Q/K + RS (d_ws). Identical value pipeline (cvt8 staging, MFMA
// order, score_exp, e*rl) -> same W as sweep-2 would have stored.
// Grid (FIXROWS/32, 4 k-splits).   [round-3 proven, single-RS read]
// ---------------------------------------------------------------------------
__global__ __launch_bounds__(256)
void k4_wfix(const float* __restrict__ Q, const float* __restrict__ Kp,
             const float* __restrict__ RS, float* __restrict__ W)
{
    __shared__ half8 sB[8 * 64];
    __shared__ float y2k[512];
    __shared__ float x2q[32];

    const int t = threadIdx.x, w = t >> 6, lane = t & 63;
    const int n = lane & 15, quad = lane >> 4;
    const int qh = w & 1, kn = w >> 1;
    const int qb = blockIdx.x * 32;          // batch 0 rows
    const int kz = blockIdx.y * 512;

#pragma unroll
    for (int j = 0; j < 2; ++j) {
        int row = t + j * 256;
        const float4* kr = (const float4*)(Kp + (size_t)(kz + row) * DD);
        float s = 0.f;
#pragma unroll
        for (int i = 0; i < 16; ++i) {
            float4 v = kr[i];
            s = fmaf(v.x,v.x,s); s = fmaf(v.y,v.y,s);
            s = fmaf(v.z,v.z,s); s = fmaf(v.w,v.w,s);
        }
        y2k[row] = s;
    }
    if (t < 32) {
        const float4* qr = (const float4*)(Q + (size_t)(qb + t) * DD);
        float s = 0.f;
#pragma unroll
        for (int i = 0; i < 16; ++i) {
            float4 v = qr[i];
            s = fmaf(v.x,v.x,s); s = fmaf(v.y,v.y,s);
            s = fmaf(v.z,v.z,s); s = fmaf(v.w,v.w,s);
        }
        x2q[t] = s;
    }
    __syncthreads();

    half8 af[2];
#pragma unroll
    for (int ds = 0; ds < 2; ++ds) {
        const float4* qp = (const float4*)(Q + (size_t)(qb + qh*16 + n) * DD + ds*32 + quad*8);
        af[ds] = cvt8(qp[0], qp[1]);
    }
    float x2r[4], rlr[4];
#pragma unroll
    for (int r = 0; r < 4; ++r) {
        int row = qb + qh * 16 + quad * 4 + r;
        x2r[r] = x2q[qh * 16 + quad * 4 + r];
        rlr[r] = __builtin_amdgcn_rcpf(RS[row]);
    }

#pragma unroll 1
    for (int kt = 0; kt < 512; kt += 64) {
        __syncthreads();
#pragma unroll
        for (int i = 0; i < 2; ++i) {
            int s = t + i * 256, f = s >> 6, l = s & 63;
            int krow = kz + kt + (f >> 1) * 16 + (l & 15);
            int dcol = (f & 1) * 32 + (l >> 4) * 8;
            const float4* kp = (const float4*)(Kp + (size_t)krow * DD + dcol);
            sB[f * 64 + l] = cvt8(kp[0], kp[1]);
        }
        __syncthreads();

        floatx4 a2[2] = {};
#pragma unroll
        for (int nt = 0; nt < 2; ++nt)
#pragma unroll
            for (int ds = 0; ds < 2; ++ds)
                a2[nt] = __builtin_amdgcn_mfma_f32_16x16x32_f16(
                    af[ds], sB[((kn * 2 + nt) * 2 + ds) * 64 + lane], a2[nt], 0, 0, 0);

#pragma unroll
        for (int nt = 0; nt < 2; ++nt) {
            int col = kn * 32 + nt * 16 + n;
            float y2 = y2k[kt + col];
#pragma unroll
            for (int r = 0; r < 4; ++r) {
                float e = score_exp(x2r[r], y2, a2[nt][r]);
                int row = qh * 16 + quad * 4 + r;
                W[(size_t)(qb + row) * NK + kz + kt + col] = e * rlr[r];
            }
        }
    }
}

// ---------------------------------------------------------------------------
extern "C" void kernel_launch(void* const* d_in, const int* in_sizes, int n_in,
                              void* d_out, int out_size, void* d_ws, size_t ws_size,
                              hipStream_t stream)
{
    const float* Q  = (const float*)d_in[0];
    const float* Kp = (const float*)d_in[1];
    const float* Vp = (const float*)d_in[2];

    float* O     = (float*)d_out;                 // (B, Nq, V)
    float* attnW = O + (size_t)BB * NQ * VV;      // (B, Nq, Nk) normalized W

    // scratch carved from W[b=0, rows<FIXROWS] (8 MB; we use 6.42 MB):
    //   Khg (2MB) | Vhg (4MB) | y2 (64KB) | x2 (64KB). k4 rewrites these rows.
    half8* Khg = (half8*)attnW;
    half8* Vhg = Khg + (size_t)BB * NT3 * 8 * 64;
    float* y2g = (float*)(Vhg + (size_t)BB * NT3 * 16 * 64);
    float* x2g = y2g + (size_t)BB * NK;

    // d_ws: only RS (64 KB -- well under the 128 KB proven safe)
    float* RS = (float*)d_ws;                     // B * NQ floats

    k0_prep<<<dim3(NK / 64, BB),     256, 0, stream>>>(Q, Kp, Vp, Khg, Vhg, y2g, x2g);
    k_main <<<dim3(BB * (NQ / 32)),  256, 0, stream>>>(Q, Khg, Vhg, y2g, x2g, attnW, O, RS);
    k4_wfix<<<dim3(FIXROWS / 32, 4), 256, 0, stream>>>(Q, Kp, RS, attnW);
}

// Round 6
// 244.451 us; speedup vs baseline: 1.4368x; 1.0637x over previous
//
#include <hip/hip_runtime.h>
#include <math.h>

#define BB 8
#define NQ 2048
#define NK 2048
#define DD 64
#define VV 128
#define EPSF 1e-7f
#define NT3 (NK / 64)   // 32 k-tiles
#define FIXROWS 1024    // W[b=0, rows<FIXROWS] is scratch during k0-k_main; k4 rewrites

typedef _Float16 half_t;
typedef half_t half8 __attribute__((ext_vector_type(8)));
typedef float  floatx4 __attribute__((ext_vector_type(4)));

// exp(-arccosh(1+tt)^2); tt from fp32 norms + fp16-MFMA cross term.
// arccosh(1+tt) = ln(1+u), u = tt + sqrt(tt*(tt+2))   (bit-identical to prior rounds)
__device__ __forceinline__ float score_exp(float x2, float y2, float xy)
{
    float px = 1.f - x2, py = 1.f - y2;
    float sq = fmaxf(x2 + y2 - 2.f * xy, 0.f);
    float dn = fmaxf(px * py, EPSF);
    float tt = fmaxf(2.f * sq * __builtin_amdgcn_rcpf(dn), EPSF);
    float u  = tt + __builtin_amdgcn_sqrtf(fmaf(tt, tt, tt + tt));
    float d  = __logf(1.f + u);
    return __expf(-d * d);
}

__device__ __forceinline__ half8 cvt8(float4 a, float4 b)
{
    half8 h;
    h[0] = (half_t)a.x; h[1] = (half_t)a.y; h[2] = (half_t)a.z; h[3] = (half_t)a.w;
    h[4] = (half_t)b.x; h[5] = (half_t)b.y; h[6] = (half_t)b.z; h[7] = (half_t)b.w;
    return h;
}

// frag-major global layouts (half8 units), matching the MFMA lane layout:
// lane l's B-operand for frag f of tile t is Khg[khg_idx(b,t,f,l)] -- so
// global-direct loads ARE the fragment loads (no LDS staging needed).
__device__ __forceinline__ size_t khg_idx(int b, int tile, int f, int l)
{ return (((size_t)b * NT3 + tile) * 8 + f) * 64 + l; }
__device__ __forceinline__ size_t vhg_idx(int b, int tile, int f, int l)
{ return (((size_t)b * NT3 + tile) * 16 + f) * 64 + l; }

// fp16 score-bounce LDS: [32 rows][64 cols] halfs, XOR-swizzled so the
// b128 frag reads hit the 8-slot floor instead of a 4-slot 16-way pile-up.
__device__ __forceinline__ int ssh_byte(int row, int col)
{
    return ((row << 7) + (col << 1)) ^ ((row & 7) << 4);
}

// ---------------------------------------------------------------------------
// K0: one-time prep into scratch (carved from W region, b=0 rows<FIXROWS).
// fp16 K-frags (2MB) + V-frags (4MB) frag-major + y2/x2 row norms.
// V path: coalesced float4 tile -> LDS bounce -> frag gather (same floats,
// same cvt order -> frags bit-identical to the proven strided version).
// Grid (NK/64, BB).
// ---------------------------------------------------------------------------
__global__ __launch_bounds__(256)
void k0_prep(const float* __restrict__ Q, const float* __restrict__ Kp,
             const float* __restrict__ V, half8* __restrict__ Khg,
             half8* __restrict__ Vhg, float* __restrict__ y2g,
             float* __restrict__ x2g)
{
    __shared__ float sVt[64 * VV];       // 32 KB fp32 V tile

    const int t = threadIdx.x, b = blockIdx.y, tile = blockIdx.x;
    const int kt = tile * 64;
    const float* Kb = Kp + (size_t)b * NK * DD;
    const float* Qb = Q  + (size_t)b * NQ * DD;
    const float* Vb = V  + (size_t)b * NK * VV;

    // coalesced V tile load: 64 rows x 128 cols = 2048 float4
#pragma unroll
    for (int i = 0; i < 8; ++i)
        ((float4*)sVt)[t + i * 256] = ((const float4*)(Vb + (size_t)kt * VV))[t + i * 256];

    // K frags: 2/thread (identical mapping + cvt8 as prior rounds)
#pragma unroll
    for (int i = 0; i < 2; ++i) {
        int s = t + i * 256, f = s >> 6, l = s & 63;
        int krow = kt + (f >> 1) * 16 + (l & 15);
        int dcol = (f & 1) * 32 + (l >> 4) * 8;
        const float4* kp = (const float4*)(Kb + (size_t)krow * DD + dcol);
        Khg[khg_idx(b, tile, f, l)] = cvt8(kp[0], kp[1]);
    }
    // norms (same fmaf chain as prior rounds)
    if (t < 64) {
        const float4* kr = (const float4*)(Kb + (size_t)(kt + t) * DD);
        float s = 0.f;
#pragma unroll
        for (int i = 0; i < 16; ++i) {
            float4 v = kr[i];
            s = fmaf(v.x,v.x,s); s = fmaf(v.y,v.y,s);
            s = fmaf(v.z,v.z,s); s = fmaf(v.w,v.w,s);
        }
        y2g[(size_t)b * NK + kt + t] = s;
    } else if (t < 128) {
        int r = t - 64;
        const float4* qr = (const float4*)(Qb + (size_t)(kt + r) * DD);
        float s = 0.f;
#pragma unroll
        for (int i = 0; i < 16; ++i) {
            float4 v = qr[i];
            s = fmaf(v.x,v.x,s); s = fmaf(v.y,v.y,s);
            s = fmaf(v.z,v.z,s); s = fmaf(v.w,v.w,s);
        }
        x2g[(size_t)b * NQ + kt + r] = s;
    }
    __syncthreads();

    // V frags from LDS (same element values + cvt as the proven gather)
#pragma unroll
    for (int i = 0; i < 4; ++i) {
        int s = t + i * 256, f = s >> 6, l = s & 63;
        int krow_l = (f & 1) * 32 + (l >> 4) * 8;
        int vcol   = (f >> 1) * 16 + (l & 15);
        half8 h;
#pragma unroll
        for (int j = 0; j < 8; ++j) h[j] = (half_t)sVt[(krow_l + j) * VV + vcol];
        Vhg[vhg_idx(b, tile, f, l)] = h;
    }
}

// ---------------------------------------------------------------------------
// K_MAIN: two proven sweeps, zero staging -- all MFMA operands loaded
// global-direct from the frag-major scratch (L2-resident per XCD).
// Sweep 1 (barrier-free): rowsum over all 2048 k -> rsumS + RS.
// Sweep 2: QK^T -> wv=e*rlr -> W store (nt) + fp16 sSh -> PV -> O = acc.
// Grid: flat 512 blocks, XCD-swizzled so each XCD owns one batch b.
// ---------------------------------------------------------------------------
__global__ __launch_bounds__(256)
void k_main(const float* __restrict__ Q, const half8* __restrict__ Khg,
            const half8* __restrict__ Vhg, const float* __restrict__ y2g,
            const float* __restrict__ x2g, float* __restrict__ W,
            float* __restrict__ O, float* __restrict__ RS)
{
    __shared__ half_t sSh[32 * 64];      // 4 KB fp16 scores bounce (XOR-swizzled)
    __shared__ float  y2k[NK];           // 8 KB
    __shared__ float  part[2][32];
    __shared__ float  rsumS[32];

    const int t = threadIdx.x, w = t >> 6, lane = t & 63;
    const int n = lane & 15, quad = lane >> 4;
    const int qh = w & 1, kh = w >> 1;

    // XCD swizzle: 512 blocks, 8 XCDs -> XCD i handles batch b=i entirely
    const int bid = blockIdx.x;
    const int swz = (bid & 7) * 64 + (bid >> 3);
    const int b = swz >> 6, qb = (swz & 63) * 32;
    const bool wskip = (b == 0) && (qb < FIXROWS);   // scratch rows: k4 rewrites

    const float* Qb = Q + (size_t)b * NQ * DD;

    // y2 full row set (2 float4/thread)
#pragma unroll
    for (int i = 0; i < 2; ++i)
        ((float4*)y2k)[t + i * 256] = ((const float4*)(y2g + (size_t)b * NK))[t + i * 256];

    half8 af[2];
#pragma unroll
    for (int ds = 0; ds < 2; ++ds) {
        const float4* qp = (const float4*)(Qb + (size_t)(qb + qh*16 + n) * DD + ds*32 + quad*8);
        af[ds] = cvt8(qp[0], qp[1]);
    }
    float x2r[4];
#pragma unroll
    for (int r = 0; r < 4; ++r)
        x2r[r] = x2g[(size_t)b * NQ + qb + qh * 16 + quad * 4 + r];
    __syncthreads();    // y2k ready

    // ============ sweep 1: row sums, barrier-free, global-direct K ==========
    const int khbase = kh * 1024;
    float srow[4] = {0.f, 0.f, 0.f, 0.f};

    half8 bf[8];
#pragma unroll
    for (int f = 0; f < 8; ++f) bf[f] = Khg[khg_idx(b, kh * 16, f, lane)];

#pragma unroll 1
    for (int kt0 = 0; kt0 < 1024; kt0 += 64) {
        const bool pf = (kt0 + 64) < 1024;
        half8 bfn[8];
        if (pf) {
#pragma unroll
            for (int f = 0; f < 8; ++f)
                bfn[f] = Khg[khg_idx(b, kh * 16 + ((kt0 + 64) >> 6), f, lane)];
        }

        floatx4 acc4[4] = {};
#pragma unroll
        for (int nt = 0; nt < 4; ++nt)
#pragma unroll
            for (int ds = 0; ds < 2; ++ds)
                acc4[nt] = __builtin_amdgcn_mfma_f32_16x16x32_f16(
                    af[ds], bf[nt * 2 + ds], acc4[nt], 0, 0, 0);

#pragma unroll
        for (int nt = 0; nt < 4; ++nt) {
            int lcol = khbase + kt0 + nt * 16 + n;
            float y2 = y2k[lcol];
#pragma unroll
            for (int r = 0; r < 4; ++r)
                srow[r] += score_exp(x2r[r], y2, acc4[nt][r]);
        }
        if (pf) {
#pragma unroll
            for (int f = 0; f < 8; ++f) bf[f] = bfn[f];
        }
    }

    // reduce over the 16 col-lanes (n)  [proven]
#pragma unroll
    for (int off = 1; off < 16; off <<= 1)
#pragma unroll
        for (int r = 0; r < 4; ++r) srow[r] += __shfl_xor(srow[r], off);
    if (n == 0)
#pragma unroll
        for (int r = 0; r < 4; ++r) part[kh][qh * 16 + quad * 4 + r] = srow[r];
    __syncthreads();
    if (t < 32) {
        float s = part[0][t] + part[1][t];
        RS[(size_t)b * NQ + qb + t] = s;    // for k4
        rsumS[t] = s;
    }
    __syncthreads();

    float rlr[4];
#pragma unroll
    for (int r = 0; r < 4; ++r)
        rlr[r] = __builtin_amdgcn_rcpf(rsumS[qh * 16 + quad * 4 + r]);

    // ============ sweep 2: scores -> W + sSh(fp16) -> PV, global-direct =====
    float* Wb = W + (size_t)b * NQ * NK;
    floatx4 acc[4] = {};

    half8 kf[4];
#pragma unroll
    for (int i = 0; i < 4; ++i) kf[i] = Khg[khg_idx(b, 0, kh * 4 + i, lane)];

#pragma unroll 1
    for (int tt = 0; tt < NT3; ++tt) {
        const bool pf = (tt + 1) < NT3;

        // B) QK^T with current K-frags
        floatx4 a2[2] = {};
#pragma unroll
        for (int nt = 0; nt < 2; ++nt)
#pragma unroll
            for (int ds = 0; ds < 2; ++ds)
                a2[nt] = __builtin_amdgcn_mfma_f32_16x16x32_f16(
                    af[ds], kf[nt * 2 + ds], a2[nt], 0, 0, 0);

        // issue V-frags (this tile) + K-frags (next tile) early: L2 latency
        // hides under the score VALU phase below
        half8 vf[8];
#pragma unroll
        for (int i = 0; i < 8; ++i) vf[i] = Vhg[vhg_idx(b, tt, kh * 8 + i, lane)];
        half8 kfn[4];
        if (pf) {
#pragma unroll
            for (int i = 0; i < 4; ++i) kfn[i] = Khg[khg_idx(b, tt + 1, kh * 4 + i, lane)];
        }

        // C) scores -> normalized W (nt store) + fp16 sSh
#pragma unroll
        for (int nt = 0; nt < 2; ++nt) {
            int col = kh * 32 + nt * 16 + n;
            int gcol = tt * 64 + col;
            float y2 = y2k[gcol];
#pragma unroll
            for (int r = 0; r < 4; ++r) {
                float e  = score_exp(x2r[r], y2, a2[nt][r]);
                float wv = e * rlr[r];
                int row = qh * 16 + quad * 4 + r;
                if (!wskip)
                    __builtin_nontemporal_store(wv, Wb + (size_t)(qb + row) * NK + gcol);
                *(half_t*)((char*)sSh + ssh_byte(row, col)) = (half_t)wv;
            }
        }
        __syncthreads();   // sSh visible

        // D) PV: A-frags straight from sSh (same fp16 bits as proven cvt8 path)
        const int row2 = qh * 16 + n;
        half8 a0 = *(const half8*)((const char*)sSh + ssh_byte(row2, quad * 8));
        half8 a1 = *(const half8*)((const char*)sSh + ssh_byte(row2, 32 + quad * 8));
#pragma unroll
        for (int nt = 0; nt < 4; ++nt) {
            acc[nt] = __builtin_amdgcn_mfma_f32_16x16x32_f16(
                a0, vf[nt * 2 + 0], acc[nt], 0, 0, 0);
            acc[nt] = __builtin_amdgcn_mfma_f32_16x16x32_f16(
                a1, vf[nt * 2 + 1], acc[nt], 0, 0, 0);
        }
        __syncthreads();   // sSh reuse protected

        if (pf) {
#pragma unroll
            for (int i = 0; i < 4; ++i) kf[i] = kfn[i];
        }
    }

    // A-frags were pre-normalized -> acc IS the output  [proven]
    float* Ob = O + (size_t)b * NQ * VV;
#pragma unroll
    for (int nt = 0; nt < 4; ++nt)
#pragma unroll
        for (int r = 0; r < 4; ++r)
            Ob[(size_t)(qb + qh * 16 + quad * 4 + r) * VV + kh * 64 + nt * 16 + n]
                = acc[nt][r];
}

// ---------------------------------------------------------------------------
// K4: rewrite W[b=0, rows<FIXROWS] (the scratch region) AFTER k_main. Reads
// ONLY raw Q/K + RS (d_ws). Identical value pipeline -> same W as sweep-2.
// Grid (FIXROWS/32, 8) = 256 blocks (1/CU), 256-col k-ranges.
// ---------------------------------------------------------------------------
__global__ __launch_bounds__(256)
void k4_wfix(const float* __restrict__ Q, const float* __restrict__ Kp,
             const float* __restrict__ RS, float* __restrict__ W)
{
    __shared__ half8 sB[8 * 64];
    __shared__ float y2k[256];
    __shared__ float x2q[32];

    const int t = threadIdx.x, w = t >> 6, lane = t & 63;
    const int n = lane & 15, quad = lane >> 4;
    const int qh = w & 1, kn = w >> 1;
    const int qb = blockIdx.x * 32;          // batch 0 rows
    const int kz = blockIdx.y * 256;

    // K norms for this 256-col range (same fmaf chain) + 32 Q norms
    {
        const float4* kr = (const float4*)(Kp + (size_t)(kz + t) * DD);
        float s = 0.f;
#pragma unroll
        for (int i = 0; i < 16; ++i) {
            float4 v = kr[i];
            s = fmaf(v.x,v.x,s); s = fmaf(v.y,v.y,s);
            s = fmaf(v.z,v.z,s); s = fmaf(v.w,v.w,s);
        }
        y2k[t] = s;
    }
    if (t < 32) {
        const float4* qr = (const float4*)(Q + (size_t)(qb + t) * DD);
        float s = 0.f;
#pragma unroll
        for (int i = 0; i < 16; ++i) {
            float4 v = qr[i];
            s = fmaf(v.x,v.x,s); s = fmaf(v.y,v.y,s);
            s = fmaf(v.z,v.z,s); s = fmaf(v.w,v.w,s);
        }
        x2q[t] = s;
    }
    __syncthreads();

    half8 af[2];
#pragma unroll
    for (int ds = 0; ds < 2; ++ds) {
        const float4* qp = (const float4*)(Q + (size_t)(qb + qh*16 + n) * DD + ds*32 + quad*8);
        af[ds] = cvt8(qp[0], qp[1]);
    }
    float x2r[4], rlr[4];
#pragma unroll
    for (int r = 0; r < 4; ++r) {
        int row = qb + qh * 16 + quad * 4 + r;
        x2r[r] = x2q[qh * 16 + quad * 4 + r];
        rlr[r] = __builtin_amdgcn_rcpf(RS[row]);
    }

#pragma unroll 1
    for (int kt = 0; kt < 256; kt += 64) {
        __syncthreads();
#pragma unroll
        for (int i = 0; i < 2; ++i) {
            int s = t + i * 256, f = s >> 6, l = s & 63;
            int krow = kz + kt + (f >> 1) * 16 + (l & 15);
            int dcol = (f & 1) * 32 + (l >> 4) * 8;
            const float4* kp = (const float4*)(Kp + (size_t)krow * DD + dcol);
            sB[f * 64 + l] = cvt8(kp[0], kp[1]);
        }
        __syncthreads();

        floatx4 a2[2] = {};
#pragma unroll
        for (int nt = 0; nt < 2; ++nt)
#pragma unroll
            for (int ds = 0; ds < 2; ++ds)
                a2[nt] = __builtin_amdgcn_mfma_f32_16x16x32_f16(
                    af[ds], sB[((kn * 2 + nt) * 2 + ds) * 64 + lane], a2[nt], 0, 0, 0);

#pragma unroll
        for (int nt = 0; nt < 2; ++nt) {
            int col = kn * 32 + nt * 16 + n;
            float y2 = y2k[kt + col];
#pragma unroll
            for (int r = 0; r < 4; ++r) {
                float e = score_exp(x2r[r], y2, a2[nt][r]);
                int row = qh * 16 + quad * 4 + r;
                W[(size_t)(qb + row) * NK + kz + kt + col] = e * rlr[r];
            }
        }
    }
}

// ---------------------------------------------------------------------------
extern "C" void kernel_launch(void* const* d_in, const int* in_sizes, int n_in,
                              void* d_out, int out_size, void* d_ws, size_t ws_size,
                              hipStream_t stream)
{
    const float* Q  = (const float*)d_in[0];
    const float* Kp = (const float*)d_in[1];
    const float* Vp = (const float*)d_in[2];

    float* O     = (float*)d_out;                 // (B, Nq, V)
    float* attnW = O + (size_t)BB * NQ * VV;      // (B, Nq, Nk) normalized W

    // scratch carved from W[b=0, rows<FIXROWS] (8 MB; we use 6.42 MB):
    //   Khg (2MB) | Vhg (4MB) | y2 (64KB) | x2 (64KB). k4 rewrites these rows.
    half8* Khg = (half8*)attnW;
    half8* Vhg = Khg + (size_t)BB * NT3 * 8 * 64;
    float* y2g = (float*)(Vhg + (size_t)BB * NT3 * 16 * 64);
    float* x2g = y2g + (size_t)BB * NK;

    // d_ws: only RS (64 KB -- well under the 128 KB proven safe)
    float* RS = (float*)d_ws;                     // B * NQ floats

    k0_prep<<<dim3(NK / 64, BB),     256, 0, stream>>>(Q, Kp, Vp, Khg, Vhg, y2g, x2g);
    k_main <<<dim3(BB * (NQ / 32)),  256, 0, stream>>>(Q, Khg, Vhg, y2g, x2g, attnW, O, RS);
    k4_wfix<<<dim3(FIXROWS / 32, 8), 256, 0, stream>>>(Q, Kp, RS, attnW);
}

// Round 8
// 209.680 us; speedup vs baseline: 1.6750x; 1.1658x over previous
//
#include <hip/hip_runtime.h>
#include <math.h>

#define BB 8
#define NQ 2048
#define NK 2048
#define DD 64
#define VV 128
#define EPSF 1e-7f
#define NT3 (NK / 64)   // 32 k-tiles
#define FIXROWS 1024    // W[b=0, rows<FIXROWS] is scratch during k0-k_main; k4 rewrites

typedef _Float16 half_t;
typedef half_t half8 __attribute__((ext_vector_type(8)));
typedef float  floatx4 __attribute__((ext_vector_type(4)));

// exp(-arccosh(1+tt)^2); tt from fp32 norms + fp16-MFMA cross term.
// arccosh(1+tt) = ln(1+u), u = tt + sqrt(tt*(tt+2)).
// exp(-d^2) with d = ln2*L, L = log2(1+u): exp2(-ln2*L*L) -- same math,
// one fused constant. fmaxf(sq,0) dropped: tt = max(2sq/dn, EPSF) clamps
// negative sq to EPSF exactly as sq=0 would (dn > 0 always).
__device__ __forceinline__ float score_exp(float x2, float y2, float xy)
{
    float sq = fmaf(-2.f, xy, x2 + y2);
    float dn = fmaxf((1.f - x2) * (1.f - y2), EPSF);
    float tt = fmaxf(2.f * sq * __builtin_amdgcn_rcpf(dn), EPSF);
    float u  = tt + __builtin_amdgcn_sqrtf(fmaf(tt, tt, tt + tt));
    float L  = __log2f(1.f + u);
    return __builtin_amdgcn_exp2f(-0.6931471805599453f * L * L);
}

__device__ __forceinline__ half8 cvt8(float4 a, float4 b)
{
    half8 h;
    h[0] = (half_t)a.x; h[1] = (half_t)a.y; h[2] = (half_t)a.z; h[3] = (half_t)a.w;
    h[4] = (half_t)b.x; h[5] = (half_t)b.y; h[6] = (half_t)b.z; h[7] = (half_t)b.w;
    return h;
}

// frag-major global layouts (half8 units), matching the MFMA lane layout:
// lane l's B-operand for frag f of tile t is Khg[khg_idx(b,t,f,l)].
// K frag f: krow-block = f>>1, d-half = f&1.  V frag f: vcol-block = f>>1,
// k-half = f&1.
__device__ __forceinline__ size_t khg_idx(int b, int tile, int f, int l)
{ return (((size_t)b * NT3 + tile) * 8 + f) * 64 + l; }
__device__ __forceinline__ size_t vhg_idx(int b, int tile, int f, int l)
{ return (((size_t)b * NT3 + tile) * 16 + f) * 64 + l; }

// fp16 score-bounce LDS: [32 rows][64 cols] halfs, XOR-swizzled (proven r6)
__device__ __forceinline__ int ssh_byte(int row, int col)
{
    return ((row << 7) + (col << 1)) ^ ((row & 7) << 4);
}

// ---------------------------------------------------------------------------
// K0: one-time prep into scratch (carved from W region, b=0 rows<FIXROWS).
// fp16 K-frags (2MB) + V-frags (4MB) frag-major + y2/x2 row norms.
// Batch-0 norms also mirrored into d_ws (wsY/wsX) so k4 does not need the
// scratch region (nor raw-K norm recompute). Grid (NK/64, BB).
// ---------------------------------------------------------------------------
__global__ __launch_bounds__(256)
void k0_prep(const float* __restrict__ Q, const float* __restrict__ Kp,
             const float* __restrict__ V, half8* __restrict__ Khg,
             half8* __restrict__ Vhg, float* __restrict__ y2g,
             float* __restrict__ x2g, float* __restrict__ wsY,
             float* __restrict__ wsX)
{
    __shared__ float sVt[64 * VV];       // 32 KB fp32 V tile

    const int t = threadIdx.x, b = blockIdx.y, tile = blockIdx.x;
    const int kt = tile * 64;
    const float* Kb = Kp + (size_t)b * NK * DD;
    const float* Qb = Q  + (size_t)b * NQ * DD;
    const float* Vb = V  + (size_t)b * NK * VV;

    // coalesced V tile load: 64 rows x 128 cols = 2048 float4
#pragma unroll
    for (int i = 0; i < 8; ++i)
        ((float4*)sVt)[t + i * 256] = ((const float4*)(Vb + (size_t)kt * VV))[t + i * 256];

    // K frags: 2/thread (identical mapping + cvt8 as prior rounds)
#pragma unroll
    for (int i = 0; i < 2; ++i) {
        int s = t + i * 256, f = s >> 6, l = s & 63;
        int krow = kt + (f >> 1) * 16 + (l & 15);
        int dcol = (f & 1) * 32 + (l >> 4) * 8;
        const float4* kp = (const float4*)(Kb + (size_t)krow * DD + dcol);
        Khg[khg_idx(b, tile, f, l)] = cvt8(kp[0], kp[1]);
    }
    // norms (same fmaf chain as prior rounds)
    if (t < 64) {
        const float4* kr = (const float4*)(Kb + (size_t)(kt + t) * DD);
        float s = 0.f;
#pragma unroll
        for (int i = 0; i < 16; ++i) {
            float4 v = kr[i];
            s = fmaf(v.x,v.x,s); s = fmaf(v.y,v.y,s);
            s = fmaf(v.z,v.z,s); s = fmaf(v.w,v.w,s);
        }
        y2g[(size_t)b * NK + kt + t] = s;
        if (b == 0) wsY[kt + t] = s;
    } else if (t < 128) {
        int r = t - 64;
        const float4* qr = (const float4*)(Qb + (size_t)(kt + r) * DD);
        float s = 0.f;
#pragma unroll
        for (int i = 0; i < 16; ++i) {
            float4 v = qr[i];
            s = fmaf(v.x,v.x,s); s = fmaf(v.y,v.y,s);
            s = fmaf(v.z,v.z,s); s = fmaf(v.w,v.w,s);
        }
        x2g[(size_t)b * NQ + kt + r] = s;
        if (b == 0) wsX[kt + r] = s;
    }
    __syncthreads();

    // V frags from LDS (same element values + cvt as the proven gather)
#pragma unroll
    for (int i = 0; i < 4; ++i) {
        int s = t + i * 256, f = s >> 6, l = s & 63;
        int krow_l = (f & 1) * 32 + (l >> 4) * 8;
        int vcol   = (f >> 1) * 16 + (l & 15);
        half8 h;
#pragma unroll
        for (int j = 0; j < 8; ++j) h[j] = (half_t)sVt[(krow_l + j) * VV + vcol];
        Vhg[vhg_idx(b, tile, f, l)] = h;
    }
}

// ---------------------------------------------------------------------------
// K_MAIN: 512 threads = 8 waves (qh = w&1 row-half, kq = w>>1 col-quarter).
// Same two proven sweeps, global-direct frags, 16 waves/CU occupancy.
// Sweep 1: rowsum; wave (qh,kq) sweeps cols kq*512..+512 (8 tiles).
// Sweep 2: per tile, wave covers cols kq*16..+15 (QK^T 2 MFMA, 4 scores),
//          W store + sSh; PV: v-colblocks {kq, kq+4} (4 MFMA), O = acc.
// Grid: flat 512 blocks, XCD-swizzled so each XCD owns one batch b.
// ---------------------------------------------------------------------------
__global__ __launch_bounds__(512, 4)
void k_main(const float* __restrict__ Q, const half8* __restrict__ Khg,
            const half8* __restrict__ Vhg, const float* __restrict__ y2g,
            const float* __restrict__ x2g, float* __restrict__ W,
            float* __restrict__ O, float* __restrict__ RS)
{
    __shared__ half_t sSh[32 * 64];      // 4 KB fp16 scores bounce (swizzled)
    __shared__ float  y2k[NK];           // 8 KB
    __shared__ float  part[4][32];
    __shared__ float  rsumS[32];

    const int t = threadIdx.x, w = t >> 6, lane = t & 63;
    const int n = lane & 15, quad = lane >> 4;
    const int qh = w & 1, kq = w >> 1;   // kq in 0..3

    // XCD swizzle: 512 blocks, 8 XCDs -> XCD i handles batch b=i entirely
    const int bid = blockIdx.x;
    const int swz = (bid & 7) * 64 + (bid >> 3);
    const int b = swz >> 6, qb = (swz & 63) * 32;
    const bool wskip = (b == 0) && (qb < FIXROWS);   // scratch rows: k4 rewrites

    const float* Qb = Q + (size_t)b * NQ * DD;

    // y2 full row set: 512 threads x 1 float4
    ((float4*)y2k)[t] = ((const float4*)(y2g + (size_t)b * NK))[t];

    half8 af[2];
#pragma unroll
    for (int ds = 0; ds < 2; ++ds) {
        const float4* qp = (const float4*)(Qb + (size_t)(qb + qh*16 + n) * DD + ds*32 + quad*8);
        af[ds] = cvt8(qp[0], qp[1]);
    }
    float x2r[4];
#pragma unroll
    for (int r = 0; r < 4; ++r)
        x2r[r] = x2g[(size_t)b * NQ + qb + qh * 16 + quad * 4 + r];
    __syncthreads();    // y2k ready

    // ============ sweep 1: row sums, barrier-free, global-direct K ==========
    float srow[4] = {0.f, 0.f, 0.f, 0.f};

    half8 bf[8];
#pragma unroll
    for (int f = 0; f < 8; ++f) bf[f] = Khg[khg_idx(b, kq * 8, f, lane)];

#pragma unroll 1
    for (int kt0 = 0; kt0 < 512; kt0 += 64) {
        const bool pf = (kt0 + 64) < 512;
        half8 bfn[8];
        if (pf) {
#pragma unroll
            for (int f = 0; f < 8; ++f)
                bfn[f] = Khg[khg_idx(b, kq * 8 + ((kt0 + 64) >> 6), f, lane)];
        }

        floatx4 acc4[4] = {};
#pragma unroll
        for (int nt = 0; nt < 4; ++nt)
#pragma unroll
            for (int ds = 0; ds < 2; ++ds)
                acc4[nt] = __builtin_amdgcn_mfma_f32_16x16x32_f16(
                    af[ds], bf[nt * 2 + ds], acc4[nt], 0, 0, 0);

#pragma unroll
        for (int nt = 0; nt < 4; ++nt) {
            int lcol = kq * 512 + kt0 + nt * 16 + n;
            float y2 = y2k[lcol];
#pragma unroll
            for (int r = 0; r < 4; ++r)
                srow[r] += score_exp(x2r[r], y2, acc4[nt][r]);
        }
        if (pf) {
#pragma unroll
            for (int f = 0; f < 8; ++f) bf[f] = bfn[f];
        }
    }

    // reduce over the 16 col-lanes (n), then over the 4 kq quarters
#pragma unroll
    for (int off = 1; off < 16; off <<= 1)
#pragma unroll
        for (int r = 0; r < 4; ++r) srow[r] += __shfl_xor(srow[r], off);
    if (n == 0)
#pragma unroll
        for (int r = 0; r < 4; ++r) part[kq][qh * 16 + quad * 4 + r] = srow[r];
    __syncthreads();
    if (t < 32) {
        float s = (part[0][t] + part[1][t]) + (part[2][t] + part[3][t]);
        RS[(size_t)b * NQ + qb + t] = s;    // for k4
        rsumS[t] = s;
    }
    __syncthreads();

    float rlr[4];
#pragma unroll
    for (int r = 0; r < 4; ++r)
        rlr[r] = __builtin_amdgcn_rcpf(rsumS[qh * 16 + quad * 4 + r]);

    // ============ sweep 2: scores -> W + sSh(fp16) -> PV, global-direct =====
    float* Wb = W + (size_t)b * NQ * NK;
    floatx4 acc[2] = {};

    half8 kf[2];
#pragma unroll
    for (int ds = 0; ds < 2; ++ds) kf[ds] = Khg[khg_idx(b, 0, kq * 2 + ds, lane)];

#pragma unroll 1
    for (int tt = 0; tt < NT3; ++tt) {
        const bool pf = (tt + 1) < NT3;

        // B) QK^T for cols kq*16..+15 (2 MFMAs over the d-halves)
        floatx4 a2 = {};
        a2 = __builtin_amdgcn_mfma_f32_16x16x32_f16(af[0], kf[0], a2, 0, 0, 0);
        a2 = __builtin_amdgcn_mfma_f32_16x16x32_f16(af[1], kf[1], a2, 0, 0, 0);

        // issue V-frags (this tile) + K-frags (next tile) early: L2 latency
        // hides under the score VALU phase below
        half8 vf[4];
        vf[0] = Vhg[vhg_idx(b, tt, kq * 2,           lane)];
        vf[1] = Vhg[vhg_idx(b, tt, kq * 2 + 1,       lane)];
        vf[2] = Vhg[vhg_idx(b, tt, (kq + 4) * 2,     lane)];
        vf[3] = Vhg[vhg_idx(b, tt, (kq + 4) * 2 + 1, lane)];
        half8 kfn[2];
        if (pf) {
#pragma unroll
            for (int ds = 0; ds < 2; ++ds)
                kfn[ds] = Khg[khg_idx(b, tt + 1, kq * 2 + ds, lane)];
        }

        // C) scores -> normalized W (nt store) + fp16 sSh
        {
            int col  = kq * 16 + n;
            int gcol = tt * 64 + col;
            float y2 = y2k[gcol];
#pragma unroll
            for (int r = 0; r < 4; ++r) {
                float e  = score_exp(x2r[r], y2, a2[r]);
                float wv = e * rlr[r];
                int row = qh * 16 + quad * 4 + r;
                if (!wskip)
                    __builtin_nontemporal_store(wv, Wb + (size_t)(qb + row) * NK + gcol);
                *(half_t*)((char*)sSh + ssh_byte(row, col)) = (half_t)wv;
            }
        }
        __syncthreads();   // sSh visible

        // D) PV: A-frags from sSh; v-colblocks kq and kq+4
        const int row2 = qh * 16 + n;
        half8 a0 = *(const half8*)((const char*)sSh + ssh_byte(row2, quad * 8));
        half8 a1 = *(const half8*)((const char*)sSh + ssh_byte(row2, 32 + quad * 8));
        acc[0] = __builtin_amdgcn_mfma_f32_16x16x32_f16(a0, vf[0], acc[0], 0, 0, 0);
        acc[0] = __builtin_amdgcn_mfma_f32_16x16x32_f16(a1, vf[1], acc[0], 0, 0, 0);
        acc[1] = __builtin_amdgcn_mfma_f32_16x16x32_f16(a0, vf[2], acc[1], 0, 0, 0);
        acc[1] = __builtin_amdgcn_mfma_f32_16x16x32_f16(a1, vf[3], acc[1], 0, 0, 0);
        __syncthreads();   // sSh reuse protected

        if (pf) { kf[0] = kfn[0]; kf[1] = kfn[1]; }
    }

    // A-frags were pre-normalized -> acc IS the output
    float* Ob = O + (size_t)b * NQ * VV;
#pragma unroll
    for (int ci = 0; ci < 2; ++ci) {
        int c = kq + ci * 4;
#pragma unroll
        for (int r = 0; r < 4; ++r)
            Ob[(size_t)(qb + qh * 16 + quad * 4 + r) * VV + c * 16 + n]
                = acc[ci][r];
    }
}

// ---------------------------------------------------------------------------
// K4: rewrite W[b=0, rows<FIXROWS] AFTER k_main. Reads raw Q/K + d_ws
// (RS + mirrored norms) -- never the scratch it overwrites. Identical value
// pipeline -> same W as sweep-2. Grid (FIXROWS/32, 16) = 512 blocks (2/CU).
// ---------------------------------------------------------------------------
__global__ __launch_bounds__(256)
void k4_wfix(const float* __restrict__ Q, const float* __restrict__ Kp,
             const float* __restrict__ RS, const float* __restrict__ wsY,
             const float* __restrict__ wsX, float* __restrict__ W)
{
    __shared__ half8 sB[8 * 64];
    __shared__ float y2k[128];
    __shared__ float x2q[32];

    const int t = threadIdx.x, w = t >> 6, lane = t & 63;
    const int n = lane & 15, quad = lane >> 4;
    const int qh = w & 1, kn = w >> 1;
    const int qb = blockIdx.x * 32;          // batch 0 rows
    const int kz = blockIdx.y * 128;

    if (t < 128) y2k[t] = wsY[kz + t];
    if (t < 32)  x2q[t] = wsX[qb + t];
    __syncthreads();

    half8 af[2];
#pragma unroll
    for (int ds = 0; ds < 2; ++ds) {
        const float4* qp = (const float4*)(Q + (size_t)(qb + qh*16 + n) * DD + ds*32 + quad*8);
        af[ds] = cvt8(qp[0], qp[1]);
    }
    float x2r[4], rlr[4];
#pragma unroll
    for (int r = 0; r < 4; ++r) {
        int row = qb + qh * 16 + quad * 4 + r;
        x2r[r] = x2q[qh * 16 + quad * 4 + r];
        rlr[r] = __builtin_amdgcn_rcpf(RS[row]);
    }

#pragma unroll 1
    for (int kt = 0; kt < 128; kt += 64) {
        __syncthreads();
#pragma unroll
        for (int i = 0; i < 2; ++i) {
            int s = t + i * 256, f = s >> 6, l = s & 63;
            int krow = kz + kt + (f >> 1) * 16 + (l & 15);
            int dcol = (f & 1) * 32 + (l >> 4) * 8;
            const float4* kp = (const float4*)(Kp + (size_t)krow * DD + dcol);
            sB[f * 64 + l] = cvt8(kp[0], kp[1]);
        }
        __syncthreads();

        floatx4 a2[2] = {};
#pragma unroll
        for (int nt = 0; nt < 2; ++nt)
#pragma unroll
            for (int ds = 0; ds < 2; ++ds)
                a2[nt] = __builtin_amdgcn_mfma_f32_16x16x32_f16(
                    af[ds], sB[((kn * 2 + nt) * 2 + ds) * 64 + lane], a2[nt], 0, 0, 0);

#pragma unroll
        for (int nt = 0; nt < 2; ++nt) {
            int col = kn * 32 + nt * 16 + n;
            float y2 = y2k[kt + col];
#pragma unroll
            for (int r = 0; r < 4; ++r) {
                float e = score_exp(x2r[r], y2, a2[nt][r]);
                int row = qh * 16 + quad * 4 + r;
                W[(size_t)(qb + row) * NK + kz + kt + col] = e * rlr[r];
            }
        }
    }
}

// ---------------------------------------------------------------------------
extern "C" void kernel_launch(void* const* d_in, const int* in_sizes, int n_in,
                              void* d_out, int out_size, void* d_ws, size_t ws_size,
                              hipStream_t stream)
{
    const float* Q  = (const float*)d_in[0];
    const float* Kp = (const float*)d_in[1];
    const float* Vp = (const float*)d_in[2];

    float* O     = (float*)d_out;                 // (B, Nq, V)
    float* attnW = O + (size_t)BB * NQ * VV;      // (B, Nq, Nk) normalized W

    // scratch carved from W[b=0, rows<FIXROWS] (8 MB; we use 6.42 MB):
    //   Khg (2MB) | Vhg (4MB) | y2 (64KB) | x2 (64KB). k4 rewrites these rows.
    half8* Khg = (half8*)attnW;
    half8* Vhg = Khg + (size_t)BB * NT3 * 8 * 64;
    float* y2g = (float*)(Vhg + (size_t)BB * NT3 * 16 * 64);
    float* x2g = y2g + (size_t)BB * NK;

    // d_ws: RS (64 KB) + batch-0 norm mirrors (16 KB) = 80 KB (<128 proven)
    float* RS  = (float*)d_ws;                    // B * NQ floats
    float* wsY = RS  + (size_t)BB * NQ;           // NK floats (b=0 K norms)
    float* wsX = wsY + NK;                        // NQ floats (b=0 Q norms)

    k0_prep<<<dim3(NK / 64, BB),      256, 0, stream>>>(Q, Kp, Vp, Khg, Vhg, y2g, x2g, wsY, wsX);
    k_main <<<dim3(BB * (NQ / 32)),   512, 0, stream>>>(Q, Khg, Vhg, y2g, x2g, attnW, O, RS);
    k4_wfix<<<dim3(FIXROWS / 32, 16), 256, 0, stream>>>(Q, Kp, RS, wsY, wsX, attnW);
}